// Round 14
// baseline (289.035 us; speedup 1.0000x reference)
//
#include <hip/hip_runtime.h>

#define NN 100000
#define NE 1600000
// IN_FEAT=128, N_HEADS=8, OUT_FEAT=16, H*F=128

static __device__ __forceinline__ unsigned short f32_to_bf16_rne(float x) {
    unsigned int u = __float_as_uint(x);
    u += 0x7fff + ((u >> 16) & 1);   // round-to-nearest-even
    return (unsigned short)(u >> 16);
}
static __device__ __forceinline__ float bf16_to_f32(unsigned int bits16) {
    return __uint_as_float(bits16 << 16);
}

// ---------------- Kernel 1: fused proj-GEMM + attention scores ----------------
// 128x128 tile per 256-thread block (16 rows/thread) to halve staging traffic per FLOP.
// X staged row-major with b128 writes; inner loop reads X as broadcast scalars
// (conflict-free) + one b128 W read per k. VALU-bound by design.
// Outputs: projT bf16 feature-major (projT[n*128 + f*8 + h]), s_src_b/s_tgt_b bf16 [N,8].
__global__ __launch_bounds__(256) void gemm_score_kernel(const float* __restrict__ x,
                                                         const float* __restrict__ W,
                                                         const float* __restrict__ a_src,
                                                         const float* __restrict__ a_tgt,
                                                         unsigned short* __restrict__ projT,
                                                         unsigned short* __restrict__ s_src_b,
                                                         unsigned short* __restrict__ s_tgt_b) {
    __shared__ float sX[128][32];   // row-major; inner-loop reads are wave-broadcast
    __shared__ float sW[32][128];
    const int t = threadIdx.x;
    const int n0 = blockIdx.x * 128;
    const int c0 = (t & 31) * 4;    // head h=c0>>4, first feat f0=c0&15
    const int r0 = t >> 5;          // 0..7; thread handles rows r0 + 8*i, i=0..15
    float acc[16][4];
#pragma unroll
    for (int i = 0; i < 16; i++)
#pragma unroll
        for (int j = 0; j < 4; j++) acc[i][j] = 0.f;

    for (int kt = 0; kt < 128; kt += 32) {
        // stage X tile: 128x32 = 1024 float4, b128 LDS writes
#pragma unroll
        for (int p = 0; p < 4; p++) {
            int idx = t + p * 256;          // 0..1023
            int r = idx >> 3;
            int kk = idx & 7;
            float4 v = make_float4(0.f, 0.f, 0.f, 0.f);
            int n = n0 + r;
            if (n < NN) v = *reinterpret_cast<const float4*>(&x[(size_t)n * 128 + kt + kk * 4]);
            *reinterpret_cast<float4*>(&sX[r][kk * 4]) = v;
        }
        // stage W tile: 32x128 = 1024 float4
#pragma unroll
        for (int p = 0; p < 4; p++) {
            int idx = t + p * 256;
            int kr = idx >> 5;
            int c4 = idx & 31;
            float4 v = *reinterpret_cast<const float4*>(&W[(size_t)(kt + kr) * 128 + c4 * 4]);
            *reinterpret_cast<float4*>(&sW[kr][c4 * 4]) = v;
        }
        __syncthreads();
#pragma unroll
        for (int k = 0; k < 32; k++) {
            float4 wv = *reinterpret_cast<const float4*>(&sW[k][c0]);
#pragma unroll
            for (int i = 0; i < 16; i++) {
                float xv = sX[r0 + 8 * i][k];
                acc[i][0] += xv * wv.x;
                acc[i][1] += xv * wv.y;
                acc[i][2] += xv * wv.z;
                acc[i][3] += xv * wv.w;
            }
        }
        __syncthreads();
    }
    const int h  = c0 >> 4;
    const int f0 = c0 & 15;
    const float aS0 = a_src[c0], aS1 = a_src[c0 + 1], aS2 = a_src[c0 + 2], aS3 = a_src[c0 + 3];
    const float aT0 = a_tgt[c0], aT1 = a_tgt[c0 + 1], aT2 = a_tgt[c0 + 2], aT3 = a_tgt[c0 + 3];
#pragma unroll
    for (int i = 0; i < 16; i++) {
        int n = n0 + r0 + 8 * i;
        if (n < NN) {
            unsigned short* pT = &projT[(size_t)n * 128];
#pragma unroll
            for (int j = 0; j < 4; j++) pT[(f0 + j) * 8 + h] = f32_to_bf16_rne(acc[i][j]);
            float ss = acc[i][0] * aS0 + acc[i][1] * aS1 + acc[i][2] * aS2 + acc[i][3] * aS3;
            float st = acc[i][0] * aT0 + acc[i][1] * aT1 + acc[i][2] * aT2 + acc[i][3] * aT3;
            ss += __shfl_xor(ss, 1);
            ss += __shfl_xor(ss, 2);
            st += __shfl_xor(st, 1);
            st += __shfl_xor(st, 2);
            if ((t & 3) == 0) {
                s_src_b[(size_t)n * 8 + h] = f32_to_bf16_rne(ss);
                s_tgt_b[(size_t)n * 8 + h] = f32_to_bf16_rne(st);
            }
        }
    }
}

// ---------------- Kernel 2: per-(edge,head) exp(leaky) -> denom (atomic only) ----------------
// Scores are bf16 and L2-resident (1.6 MB each); no exb materialization — the
// aggregate pass recomputes ex from the SAME bf16 inputs (bit-identical alpha).
__global__ __launch_bounds__(256) void denom_kernel(const int* __restrict__ src,
                                                    const int* __restrict__ tgt,
                                                    const unsigned short* __restrict__ s_src_b,
                                                    const unsigned short* __restrict__ s_tgt_b,
                                                    float* __restrict__ denom) {
    int gid = blockIdx.x * blockDim.x + threadIdx.x;
    int e = gid >> 3;
    if (e >= NE) return;
    int h = gid & 7;
    int s = src[e], t = tgt[e];
    float v = bf16_to_f32(s_src_b[(size_t)s * 8 + h]) + bf16_to_f32(s_tgt_b[(size_t)t * 8 + h]);
    v = v >= 0.f ? v : 0.2f * v;
    atomicAdd(&denom[(size_t)t * 8 + h], expf(v));
}

// ---------------- Kernel 3: per-edge alpha (recomputed), head-reduced message, scatter-add ----------------
__global__ __launch_bounds__(256) void aggregate_kernel(const int* __restrict__ src,
                                                        const int* __restrict__ tgt,
                                                        const unsigned short* __restrict__ s_src_b,
                                                        const unsigned short* __restrict__ s_tgt_b,
                                                        const float* __restrict__ denom,
                                                        const unsigned short* __restrict__ projT,
                                                        float* __restrict__ out_acc) {
    int gid = blockIdx.x * blockDim.x + threadIdx.x;
    int e = gid >> 4;
    int lane = gid & 15;   // output feature f
    if (e >= NE) return;
    int s = src[e], t = tgt[e];
    int h = lane & 7;
    float v0 = bf16_to_f32(s_src_b[(size_t)s * 8 + h]) + bf16_to_f32(s_tgt_b[(size_t)t * 8 + h]);
    v0 = v0 >= 0.f ? v0 : 0.2f * v0;
    float ex = expf(v0);
    float alpha = ex / (denom[(size_t)t * 8 + h] + 1e-16f);
    // gather 8 heads at feature 'lane': 16 bytes
    uint4 v = *reinterpret_cast<const uint4*>(&projT[(size_t)s * 128 + lane * 8]);
    float p0 = bf16_to_f32(v.x & 0xffffu), p1 = bf16_to_f32(v.x >> 16);
    float p2 = bf16_to_f32(v.y & 0xffffu), p3 = bf16_to_f32(v.y >> 16);
    float p4 = bf16_to_f32(v.z & 0xffffu), p5 = bf16_to_f32(v.z >> 16);
    float p6 = bf16_to_f32(v.w & 0xffffu), p7 = bf16_to_f32(v.w >> 16);
    float m = 0.f;
    m += __shfl(alpha, 0, 16) * p0;
    m += __shfl(alpha, 1, 16) * p1;
    m += __shfl(alpha, 2, 16) * p2;
    m += __shfl(alpha, 3, 16) * p3;
    m += __shfl(alpha, 4, 16) * p4;
    m += __shfl(alpha, 5, 16) * p5;
    m += __shfl(alpha, 6, 16) * p6;
    m += __shfl(alpha, 7, 16) * p7;
    atomicAdd(&out_acc[(size_t)t * 16 + lane], m * 0.125f);
}

// ---------------- Kernel 4: bias + softmax over 16 features ----------------
__global__ __launch_bounds__(256) void softmax_kernel(const float* __restrict__ out_acc,
                                                      const float* __restrict__ bias,
                                                      float* __restrict__ out) {
    int gid = blockIdx.x * blockDim.x + threadIdx.x;
    int n = gid >> 4;
    int lane = gid & 15;
    if (n >= NN) return;
    float v = out_acc[(size_t)n * 16 + lane] + bias[lane];
    float mx = v;
#pragma unroll
    for (int m = 1; m < 16; m <<= 1) mx = fmaxf(mx, __shfl_xor(mx, m, 64));
    float ex = expf(v - mx);
    float sum = ex;
#pragma unroll
    for (int m = 1; m < 16; m <<= 1) sum += __shfl_xor(sum, m, 64);
    out[(size_t)n * 16 + lane] = ex / sum;
}

extern "C" void kernel_launch(void* const* d_in, const int* in_sizes, int n_in,
                              void* d_out, int out_size, void* d_ws, size_t ws_size,
                              hipStream_t stream) {
    const float* x     = (const float*)d_in[0];
    const int*   ei    = (const int*)d_in[1];
    const float* W     = (const float*)d_in[2];
    const float* a_src = (const float*)d_in[3];
    const float* a_tgt = (const float*)d_in[4];
    const float* bias  = (const float*)d_in[5];
    float* out = (float*)d_out;

    const int* src = ei;            // edge_index[0]
    const int* tgt = ei + NE;       // edge_index[1]

    char* ws = (char*)d_ws;
    size_t off = 0;
    auto alloc = [&](size_t bytes) {
        char* p = ws + off;
        off += (bytes + 255) & ~(size_t)255;
        return p;
    };
    unsigned short* projT   = (unsigned short*)alloc((size_t)NN * 128 * 2); // 25.6 MB bf16, f-major
    unsigned short* s_src_b = (unsigned short*)alloc((size_t)NN * 8 * 2);   // 1.6 MB
    unsigned short* s_tgt_b = (unsigned short*)alloc((size_t)NN * 8 * 2);   // 1.6 MB
    float*          denom   = (float*)alloc((size_t)NN * 8 * 4);            // 3.2 MB
    float*          out_acc = (float*)alloc((size_t)NN * 16 * 4);           // 6.4 MB

    // zero accumulators every call (harness does not re-poison between replays)
    hipMemsetAsync(denom, 0, (size_t)NN * 8 * 4, stream);
    hipMemsetAsync(out_acc, 0, (size_t)NN * 16 * 4, stream);

    gemm_score_kernel<<<(NN + 127) / 128, 256, 0, stream>>>(x, W, a_src, a_tgt, projT, s_src_b, s_tgt_b);
    denom_kernel<<<((size_t)NE * 8 + 255) / 256, 256, 0, stream>>>(src, tgt, s_src_b, s_tgt_b, denom);
    aggregate_kernel<<<((size_t)NE * 16 + 255) / 256, 256, 0, stream>>>(src, tgt, s_src_b, s_tgt_b,
                                                                        denom, projT, out_acc);
    softmax_kernel<<<(NN * 16 + 255) / 256, 256, 0, stream>>>(out_acc, bias, out);
}

// Round 15
// 252.283 us; speedup vs baseline: 1.1457x; 1.1457x over previous
//
#include <hip/hip_runtime.h>

#define NN 100000
#define NE 1600000
// IN_FEAT=128, N_HEADS=8, OUT_FEAT=16, H*F=128

static __device__ __forceinline__ unsigned short f32_to_bf16_rne(float x) {
    unsigned int u = __float_as_uint(x);
    u += 0x7fff + ((u >> 16) & 1);   // round-to-nearest-even
    return (unsigned short)(u >> 16);
}
static __device__ __forceinline__ float bf16_to_f32(unsigned int bits16) {
    return __uint_as_float(bits16 << 16);
}

// pack layout per node n (64 B, one cache line):
//   u16 idx n*32 + h      : bf16 s_tgt[h]          (bytes 0..15)
//   f32 idx n*16 + 4 + h  : f32 denom[h]           (bytes 16..47)
//   bytes 48..63 pad
// -> denom pass touches ONE random tgt line per edge (read s_tgt + atomic denom).

// ---------------- Kernel 1: fused proj-GEMM + attention scores ----------------
// 64-row tile (round-13-measured version). Outputs projT bf16 f-major, s_src_b bf16,
// pack (s_tgt bf16 + zeroed denom slots — no separate memset needed).
__global__ __launch_bounds__(256) void gemm_score_kernel(const float* __restrict__ x,
                                                         const float* __restrict__ W,
                                                         const float* __restrict__ a_src,
                                                         const float* __restrict__ a_tgt,
                                                         unsigned short* __restrict__ projT,
                                                         unsigned short* __restrict__ s_src_b,
                                                         float* __restrict__ pack) {
    __shared__ float sXT[32][68];   // k-major, padded
    __shared__ float sW[32][128];
    const int t = threadIdx.x;
    const int n0 = blockIdx.x * 64;
    const int c0 = (t & 31) * 4;    // head h=c0>>4, first feat f0=c0&15
    const int r0 = t >> 5;          // row group 0..7
    float acc[8][4];
#pragma unroll
    for (int i = 0; i < 8; i++)
#pragma unroll
        for (int j = 0; j < 4; j++) acc[i][j] = 0.f;

    for (int kt = 0; kt < 128; kt += 32) {
#pragma unroll
        for (int p = 0; p < 2; p++) {
            int idx = t + p * 256;
            int r = idx >> 3;
            int kk = idx & 7;
            float4 v = make_float4(0.f, 0.f, 0.f, 0.f);
            int n = n0 + r;
            if (n < NN) v = *reinterpret_cast<const float4*>(&x[(size_t)n * 128 + kt + kk * 4]);
            sXT[kk * 4 + 0][r] = v.x;
            sXT[kk * 4 + 1][r] = v.y;
            sXT[kk * 4 + 2][r] = v.z;
            sXT[kk * 4 + 3][r] = v.w;
        }
#pragma unroll
        for (int p = 0; p < 4; p++) {
            int idx = t + p * 256;
            int kr = idx >> 5;
            int c4 = idx & 31;
            float4 v = *reinterpret_cast<const float4*>(&W[(size_t)(kt + kr) * 128 + c4 * 4]);
            *reinterpret_cast<float4*>(&sW[kr][c4 * 4]) = v;
        }
        __syncthreads();
#pragma unroll
        for (int k = 0; k < 32; k++) {
            float4 xa = *reinterpret_cast<const float4*>(&sXT[k][r0 * 8]);
            float4 xb = *reinterpret_cast<const float4*>(&sXT[k][r0 * 8 + 4]);
            float4 wv = *reinterpret_cast<const float4*>(&sW[k][c0]);
            float xs[8] = {xa.x, xa.y, xa.z, xa.w, xb.x, xb.y, xb.z, xb.w};
#pragma unroll
            for (int i = 0; i < 8; i++) {
                acc[i][0] += xs[i] * wv.x;
                acc[i][1] += xs[i] * wv.y;
                acc[i][2] += xs[i] * wv.z;
                acc[i][3] += xs[i] * wv.w;
            }
        }
        __syncthreads();
    }
    const int h  = c0 >> 4;
    const int f0 = c0 & 15;
    const float aS0 = a_src[c0], aS1 = a_src[c0 + 1], aS2 = a_src[c0 + 2], aS3 = a_src[c0 + 3];
    const float aT0 = a_tgt[c0], aT1 = a_tgt[c0 + 1], aT2 = a_tgt[c0 + 2], aT3 = a_tgt[c0 + 3];
#pragma unroll
    for (int i = 0; i < 8; i++) {
        int n = n0 + r0 * 8 + i;
        if (n < NN) {
            unsigned short* pT = &projT[(size_t)n * 128];
#pragma unroll
            for (int j = 0; j < 4; j++) pT[(f0 + j) * 8 + h] = f32_to_bf16_rne(acc[i][j]);
            float ss = acc[i][0] * aS0 + acc[i][1] * aS1 + acc[i][2] * aS2 + acc[i][3] * aS3;
            float st = acc[i][0] * aT0 + acc[i][1] * aT1 + acc[i][2] * aT2 + acc[i][3] * aT3;
            ss += __shfl_xor(ss, 1);
            ss += __shfl_xor(ss, 2);
            st += __shfl_xor(st, 1);
            st += __shfl_xor(st, 2);
            if ((t & 3) == 0) {
                s_src_b[(size_t)n * 8 + h] = f32_to_bf16_rne(ss);
                reinterpret_cast<unsigned short*>(pack)[(size_t)n * 32 + h] = f32_to_bf16_rne(st);
                pack[(size_t)n * 16 + 4 + h] = 0.f;   // zero denom slot inline
            }
        }
    }
}

// ---------------- Kernel 2: per-(edge,head) exp(leaky) -> denom + store ex (bf16) ----------------
// Per edge: 2 random lines (src score line, tgt pack line). exb streaming write.
__global__ __launch_bounds__(256) void denom_kernel(const int* __restrict__ src,
                                                    const int* __restrict__ tgt,
                                                    const unsigned short* __restrict__ s_src_b,
                                                    float* __restrict__ pack,
                                                    unsigned short* __restrict__ exb) {
    int gid = blockIdx.x * blockDim.x + threadIdx.x;
    int e = gid >> 3;
    if (e >= NE) return;
    int h = gid & 7;
    int s = src[e], t = tgt[e];
    float st = bf16_to_f32(reinterpret_cast<const unsigned short*>(pack)[(size_t)t * 32 + h]);
    float v = bf16_to_f32(s_src_b[(size_t)s * 8 + h]) + st;
    v = v >= 0.f ? v : 0.2f * v;
    float ex = expf(v);
    exb[(size_t)e * 8 + h] = f32_to_bf16_rne(ex);
    atomicAdd(&pack[(size_t)t * 16 + 4 + h], ex);
}

// ---------------- Kernel 3: per-edge alpha from stored ex, head-reduced message, scatter-add ----------------
__global__ __launch_bounds__(256) void aggregate_kernel(const int* __restrict__ src,
                                                        const int* __restrict__ tgt,
                                                        const float* __restrict__ pack,
                                                        const unsigned short* __restrict__ exb,
                                                        const unsigned short* __restrict__ projT,
                                                        float* __restrict__ out_acc) {
    int gid = blockIdx.x * blockDim.x + threadIdx.x;
    int e = gid >> 4;
    int lane = gid & 15;   // output feature f
    if (e >= NE) return;
    int s = src[e], t = tgt[e];
    int h = lane & 7;
    float ex = bf16_to_f32(exb[(size_t)e * 8 + h]);
    float alpha = ex / (pack[(size_t)t * 16 + 4 + h] + 1e-16f);
    // gather 8 heads at feature 'lane': 16 bytes
    uint4 v = *reinterpret_cast<const uint4*>(&projT[(size_t)s * 128 + lane * 8]);
    float p0 = bf16_to_f32(v.x & 0xffffu), p1 = bf16_to_f32(v.x >> 16);
    float p2 = bf16_to_f32(v.y & 0xffffu), p3 = bf16_to_f32(v.y >> 16);
    float p4 = bf16_to_f32(v.z & 0xffffu), p5 = bf16_to_f32(v.z >> 16);
    float p6 = bf16_to_f32(v.w & 0xffffu), p7 = bf16_to_f32(v.w >> 16);
    float m = 0.f;
    m += __shfl(alpha, 0, 16) * p0;
    m += __shfl(alpha, 1, 16) * p1;
    m += __shfl(alpha, 2, 16) * p2;
    m += __shfl(alpha, 3, 16) * p3;
    m += __shfl(alpha, 4, 16) * p4;
    m += __shfl(alpha, 5, 16) * p5;
    m += __shfl(alpha, 6, 16) * p6;
    m += __shfl(alpha, 7, 16) * p7;
    atomicAdd(&out_acc[(size_t)t * 16 + lane], m * 0.125f);
}

// ---------------- Kernel 4: bias + softmax over 16 features ----------------
__global__ __launch_bounds__(256) void softmax_kernel(const float* __restrict__ out_acc,
                                                      const float* __restrict__ bias,
                                                      float* __restrict__ out) {
    int gid = blockIdx.x * blockDim.x + threadIdx.x;
    int n = gid >> 4;
    int lane = gid & 15;
    if (n >= NN) return;
    float v = out_acc[(size_t)n * 16 + lane] + bias[lane];
    float mx = v;
#pragma unroll
    for (int m = 1; m < 16; m <<= 1) mx = fmaxf(mx, __shfl_xor(mx, m, 64));
    float ex = expf(v - mx);
    float sum = ex;
#pragma unroll
    for (int m = 1; m < 16; m <<= 1) sum += __shfl_xor(sum, m, 64);
    out[(size_t)n * 16 + lane] = ex / sum;
}

extern "C" void kernel_launch(void* const* d_in, const int* in_sizes, int n_in,
                              void* d_out, int out_size, void* d_ws, size_t ws_size,
                              hipStream_t stream) {
    const float* x     = (const float*)d_in[0];
    const int*   ei    = (const int*)d_in[1];
    const float* W     = (const float*)d_in[2];
    const float* a_src = (const float*)d_in[3];
    const float* a_tgt = (const float*)d_in[4];
    const float* bias  = (const float*)d_in[5];
    float* out = (float*)d_out;

    const int* src = ei;            // edge_index[0]
    const int* tgt = ei + NE;       // edge_index[1]

    char* ws = (char*)d_ws;
    size_t off = 0;
    auto alloc = [&](size_t bytes) {
        char* p = ws + off;
        off += (bytes + 255) & ~(size_t)255;
        return p;
    };
    unsigned short* projT   = (unsigned short*)alloc((size_t)NN * 128 * 2); // 25.6 MB bf16, f-major
    unsigned short* exb     = (unsigned short*)alloc((size_t)NE * 8 * 2);   // 25.6 MB bf16 ex[e][h]
    unsigned short* s_src_b = (unsigned short*)alloc((size_t)NN * 8 * 2);   // 1.6 MB
    float*          pack    = (float*)alloc((size_t)NN * 64);               // 6.4 MB node lines
    float*          out_acc = (float*)alloc((size_t)NN * 16 * 4);           // 6.4 MB

    // out_acc must be zeroed every call (denom slots in pack are zeroed by gemm)
    hipMemsetAsync(out_acc, 0, (size_t)NN * 16 * 4, stream);

    gemm_score_kernel<<<(NN + 63) / 64, 256, 0, stream>>>(x, W, a_src, a_tgt, projT, s_src_b, pack);
    denom_kernel<<<((size_t)NE * 8 + 255) / 256, 256, 0, stream>>>(src, tgt, s_src_b, pack, exb);
    aggregate_kernel<<<((size_t)NE * 16 + 255) / 256, 256, 0, stream>>>(src, tgt, pack, exb,
                                                                        projT, out_acc);
    softmax_kernel<<<(NN * 16 + 255) / 256, 256, 0, stream>>>(out_acc, bias, out);
}